// Round 10
// baseline (85.168 us; speedup 1.0000x reference)
//
#include <hip/hip_runtime.h>
#include <hip/hip_bf16.h>

// Problem constants (fixed by the reference)
#define B_DIM   8
#define S_LEN   4096
#define H_DIM   1024
#define HID_DIM 128
#define NSPEC   5
#define NROWS   (HID_DIM + 1 + NSPEC)   // 129 interval rows + 5 special rows = 134
#define SLOPE   0.01f
#define LN_EPS  1e-12f
#define NITER   8                        // tokens per wave (same pos row)

// native clang vector for nontemporal stores (HIP float4 is a class type,
// which __builtin_nontemporal_store rejects)
typedef float vfloat4 __attribute__((ext_vector_type(4)));

// ---------------------------------------------------------------------------
// Kernel 1: build table rows.
//   rows 0..128 : interval i -> (u_i, v_i) with expr_e(x) = x*u + v (b2 folded)
//   rows 129..133: special m -> (0, leaky(special_emb[m]) @ W2 + b2)
// Block 0 additionally publishes the raw breakpoints t_k (unsorted) for fuse;
// interval membership there is the order-independent count #{k: t_k <= x}.
// ---------------------------------------------------------------------------
__global__ __launch_bounds__(256) void build_kernel(
        const float* __restrict__ W1,
        const float* __restrict__ b1,
        const float* __restrict__ W2,
        const float* __restrict__ b2,
        const float* __restrict__ spec,
        float* __restrict__ tvals,
        float2* __restrict__ tab) {
    const int row = blockIdx.x;
    const int tid = threadIdx.x;

    __shared__ float tsh[HID_DIM];
    __shared__ float ash[HID_DIM];
    __shared__ float csh[HID_DIM];

    float w = 0.0f, b = 0.0f, t = 0.0f;
    if (tid < HID_DIM) {
        w = W1[tid];
        b = b1[tid];
        t = (w != 0.0f) ? (-b / w) : __builtin_inff();
        tsh[tid] = t;
        if (row == 0) tvals[tid] = t;    // raw breakpoints for the fuse ballot
    }
    __syncthreads();
    if (tid < HID_DIM) {
        // stable rank of t among all breakpoints (defines interval membership)
        int r = 0;
        #pragma unroll 8
        for (int k2 = 0; k2 < HID_DIM; ++k2) {
            const float t2 = tsh[k2];
            if (t2 < t || (t2 == t && k2 < tid)) ++r;
        }

        float a, c;
        if (row <= HID_DIM) {
            const bool crossed = (r < row);              // t_k <= x in interval
            bool zpos;
            if (w > 0.0f)      zpos = crossed;
            else if (w < 0.0f) zpos = !crossed;
            else               zpos = (b >= 0.0f);
            const float s = zpos ? 1.0f : (SLOPE * SLOPE);
            a = s * w;
            c = s * b;
        } else {
            const int m = row - (HID_DIM + 1);
            const float e = spec[m * HID_DIM + tid];
            a = 0.0f;
            c = (e >= 0.0f) ? e : SLOPE * e;
        }
        ash[tid] = a;
        csh[tid] = c;
    }
    __syncthreads();

    // thread handles columns [4*tid .. 4*tid+3]
    float4 u = make_float4(0.f, 0.f, 0.f, 0.f);
    float4 v = make_float4(0.f, 0.f, 0.f, 0.f);
    #pragma unroll 4
    for (int k = 0; k < HID_DIM; ++k) {
        const float4 w2 = reinterpret_cast<const float4*>(W2 + (size_t)k * H_DIM)[tid];
        const float a = ash[k], c = csh[k];
        u.x = fmaf(a, w2.x, u.x);  v.x = fmaf(c, w2.x, v.x);
        u.y = fmaf(a, w2.y, u.y);  v.y = fmaf(c, w2.y, v.y);
        u.z = fmaf(a, w2.z, u.z);  v.z = fmaf(c, w2.z, v.z);
        u.w = fmaf(a, w2.w, u.w);  v.w = fmaf(c, w2.w, v.w);
    }
    const float4 bb = reinterpret_cast<const float4*>(b2)[tid];
    float4* trow = reinterpret_cast<float4*>(tab + (size_t)row * H_DIM);
    trow[2 * tid]     = make_float4(u.x, v.x + bb.x, u.y, v.y + bb.y);
    trow[2 * tid + 1] = make_float4(u.z, v.z + bb.z, u.w, v.w + bb.w);
}

// ---------------------------------------------------------------------------
// Kernel 2: fused gather + table MLP + pos add + LayerNorm.
// NITER=8 tokens per wave (token stride S_LEN => one pos row per wave).
// ASYMMETRIC pipeline matched to latency class:
//   - scalars (expr/gid)  : 3 iterations ahead
//   - gene row (L3/HBM)   : 2 iterations ahead  (the long pole, ~500-900cy)
//   - tab row  (L2-hot)   : 1 iteration ahead   (~300cy)
// pos + gamma/beta live in LDS (pos is wave-private: no barrier needed),
// freeing VGPRs for the 3rd gene staging set. Target <=170 VGPR so
// __launch_bounds__(256,3) holds 3 waves/SIMD.
// ---------------------------------------------------------------------------
__global__ __launch_bounds__(256, 3) void fuse_kernel(
        const int*   __restrict__ gene_ids,
        const float* __restrict__ expr,
        const float* __restrict__ gene_emb,
        const float* __restrict__ pos_emb,
        const float* __restrict__ gamma,
        const float* __restrict__ beta,
        const float* __restrict__ tvals,
        const float2* __restrict__ tab,
        float* __restrict__ out) {
    const int tid  = threadIdx.x;
    const int lane = tid & 63;
    const int wv   = tid >> 6;
    const int w    = blockIdx.x * 4 + wv;   // wave id = pos row, 0..4095

    __shared__ float4 gm_lds[H_DIM / 4];        // 4 KB
    __shared__ float4 bt_lds[H_DIM / 4];        // 4 KB
    __shared__ float4 pos_lds[4][H_DIM / 4];    // 16 KB (wave-private rows)

    gm_lds[tid] = reinterpret_cast<const float4*>(gamma)[tid];
    bt_lds[tid] = reinterpret_cast<const float4*>(beta)[tid];

    // breakpoints once per wave
    const float tka = tvals[lane];
    const float tkb = tvals[lane + 64];

    // stage this wave's pos row into LDS (wave-private -> no barrier needed)
    {
        const float4* pp = reinterpret_cast<const float4*>(pos_emb + (size_t)w * H_DIM);
        #pragma unroll
        for (int q = 0; q < 4; ++q) pos_lds[wv][lane + 64 * q] = pp[lane + 64 * q];
    }

    __syncthreads();    // gamma/beta staged (block-wide)

    // ---- prologue: scalars for i=0,1,2; gene staging i=0,1; tab staging i=0
    float x0 = expr[w];
    int   g0 = gene_ids[w];
    float x1 = expr[w + S_LEN];
    int   g1 = gene_ids[w + S_LEN];
    float x2 = expr[w + 2 * S_LEN];
    int   g2 = gene_ids[w + 2 * S_LEN];

    float4 g_c[4], g_n1[4], ta_c[4], tb_c[4];
    {
        const float4* gpc = reinterpret_cast<const float4*>(gene_emb + (size_t)g0 * H_DIM);
        const float4* gpn = reinterpret_cast<const float4*>(gene_emb + (size_t)g1 * H_DIM);
        #pragma unroll
        for (int q = 0; q < 4; ++q) {
            const int f = lane + 64 * q;
            g_c[q]  = gpc[f];
            g_n1[q] = gpn[f];
        }
    }
    float xm_c;
    {
        const int rc = __popcll(__ballot(tka <= x0)) + __popcll(__ballot(tkb <= x0));
        const bool sc = (x0 < 0.0f);
        const int  mc = min(max(-((int)x0) - 1, 0), NSPEC - 1);
        const int  row = sc ? (HID_DIM + 1 + mc) : rc;
        xm_c = sc ? 0.0f : x0;
        const float4* tp = reinterpret_cast<const float4*>(tab + (size_t)row * H_DIM);
        #pragma unroll
        for (int q = 0; q < 4; ++q) {
            const int f = lane + 64 * q;
            ta_c[q] = tp[2 * f];
            tb_c[q] = tp[2 * f + 1];
        }
    }

    // pipeline scalar state: x_a = x[i+1], x_b = x[i+2], gid_b = gid[i+2]
    float x_a = x1, x_b = x2;
    int   gid_b = g2;

    #pragma unroll
    for (int i = 0; i < NITER; ++i) {
        const int t = w + i * S_LEN;

        // ---- scalars for i+3 (3-ahead; compile-time guard)
        float x_in = 0.0f;
        int   gid_in = 0;
        if (i + 3 < NITER) {
            x_in   = expr[t + 3 * S_LEN];
            gid_in = gene_ids[t + 3 * S_LEN];
        }

        // ---- gene staging for i+2 (2-ahead; the long-latency gather)
        float4 g_n2[4];
        if (i + 2 < NITER) {
            const float4* gp = reinterpret_cast<const float4*>(gene_emb + (size_t)gid_b * H_DIM);
            #pragma unroll
            for (int q = 0; q < 4; ++q) g_n2[q] = gp[lane + 64 * q];
        }

        // ---- tab staging for i+1 (1-ahead; L2-hot)
        float xm_n = 0.0f;
        float4 ta_n[4], tb_n[4];
        if (i + 1 < NITER) {
            const int rc = __popcll(__ballot(tka <= x_a)) + __popcll(__ballot(tkb <= x_a));
            const bool sn = (x_a < 0.0f);
            const int  mn = min(max(-((int)x_a) - 1, 0), NSPEC - 1);
            const int  rown = sn ? (HID_DIM + 1 + mn) : rc;
            xm_n = sn ? 0.0f : x_a;
            const float4* tp = reinterpret_cast<const float4*>(tab + (size_t)rown * H_DIM);
            #pragma unroll
            for (int q = 0; q < 4; ++q) {
                const int f = lane + 64 * q;
                ta_n[q] = tp[2 * f];
                tb_n[q] = tp[2 * f + 1];
            }
        }

        // ---- consume current staging: e + moments (pos from wave-private LDS)
        float4 e[4];
        float s1 = 0.0f, s2 = 0.0f;
        #pragma unroll
        for (int q = 0; q < 4; ++q) {
            const float4 pq = pos_lds[wv][lane + 64 * q];
            float4 ev;
            ev.x = g_c[q].x + fmaf(xm_c, ta_c[q].x, ta_c[q].y) + pq.x;
            ev.y = g_c[q].y + fmaf(xm_c, ta_c[q].z, ta_c[q].w) + pq.y;
            ev.z = g_c[q].z + fmaf(xm_c, tb_c[q].x, tb_c[q].y) + pq.z;
            ev.w = g_c[q].w + fmaf(xm_c, tb_c[q].z, tb_c[q].w) + pq.w;
            e[q] = ev;
            s1 += ev.x + ev.y + ev.z + ev.w;
            s2 += ev.x * ev.x + ev.y * ev.y + ev.z * ev.z + ev.w * ev.w;
        }

        // ---- 64-lane butterfly reduction (no LDS, no barrier)
        #pragma unroll
        for (int off = 32; off >= 1; off >>= 1) {
            s1 += __shfl_xor(s1, off, 64);
            s2 += __shfl_xor(s2, off, 64);
        }

        const float inv  = 1.0f / (float)H_DIM;
        const float mu   = s1 * inv;
        const float rsig = rsqrtf(s2 * inv - mu * mu + LN_EPS);

        // ---- LN epilogue: gamma/beta from LDS, NT stores
        vfloat4* op = reinterpret_cast<vfloat4*>(out + (size_t)t * H_DIM);
        #pragma unroll
        for (int q = 0; q < 4; ++q) {
            const int f = lane + 64 * q;
            const float4 gm = gm_lds[f];
            const float4 bt = bt_lds[f];
            vfloat4 o;
            o.x = fmaf((e[q].x - mu) * rsig, gm.x, bt.x);
            o.y = fmaf((e[q].y - mu) * rsig, gm.y, bt.y);
            o.z = fmaf((e[q].z - mu) * rsig, gm.z, bt.z);
            o.w = fmaf((e[q].w - mu) * rsig, gm.w, bt.w);
            __builtin_nontemporal_store(o, op + f);
        }

        // ---- shift pipeline (fully unrolled => compiler renames, no movs)
        xm_c  = xm_n;
        x_a   = x_b;
        x_b   = x_in;
        gid_b = gid_in;
        #pragma unroll
        for (int q = 0; q < 4; ++q) {
            g_c[q]  = g_n1[q];
            g_n1[q] = g_n2[q];
            ta_c[q] = ta_n[q];
            tb_c[q] = tb_n[q];
        }
    }
}

// ---------------------------------------------------------------------------
extern "C" void kernel_launch(void* const* d_in, const int* in_sizes, int n_in,
                              void* d_out, int out_size, void* d_ws, size_t ws_size,
                              hipStream_t stream) {
    const int*   gene_ids = (const int*)  d_in[0];
    const float* expr     = (const float*)d_in[1];
    const float* gene_emb = (const float*)d_in[2];
    const float* W1       = (const float*)d_in[3];
    const float* b1       = (const float*)d_in[4];
    const float* W2       = (const float*)d_in[5];
    const float* b2       = (const float*)d_in[6];
    const float* spec     = (const float*)d_in[7];
    const float* pos_emb  = (const float*)d_in[8];
    const float* gamma    = (const float*)d_in[9];
    const float* beta     = (const float*)d_in[10];
    float* out = (float*)d_out;

    // workspace layout
    const size_t tab_bytes = (size_t)NROWS * H_DIM * sizeof(float2);  // ~1.07 MB
    float2* tab   = (float2*)d_ws;
    float*  tvals = (float*)((char*)d_ws + tab_bytes);

    const int n_tokens = in_sizes[0];       // B*S = 32768
    const int nwaves   = n_tokens / NITER;  // 4096 waves, one pos row each

    build_kernel<<<NROWS, 256, 0, stream>>>(W1, b1, W2, b2, spec, tvals, tab);
    fuse_kernel<<<nwaves / 4, 256, 0, stream>>>(gene_ids, expr, gene_emb, pos_emb,
                                                gamma, beta, tvals, tab, out);
}

// Round 11
// 64.408 us; speedup vs baseline: 1.3223x; 1.3223x over previous
//
#include <hip/hip_runtime.h>
#include <hip/hip_bf16.h>

// Problem constants (fixed by the reference)
#define B_DIM   8
#define S_LEN   4096
#define H_DIM   1024
#define HID_DIM 128
#define NSPEC   5
#define NROWS   (HID_DIM + 1 + NSPEC)   // 129 interval rows + 5 special rows = 134
#define SLOPE   0.01f
#define LN_EPS  1e-12f
#define NITER   8                        // tokens per wave (same pos row)

// native clang vector for nontemporal stores (HIP float4 is a class type,
// which __builtin_nontemporal_store rejects)
typedef float vfloat4 __attribute__((ext_vector_type(4)));

// ---------------------------------------------------------------------------
// Kernel 1: build table rows.
//   rows 0..128 : interval i -> (u_i, v_i) with expr_e(x) = x*u + v (b2 folded)
//   rows 129..133: special m -> (0, leaky(special_emb[m]) @ W2 + b2)
// Block 0 additionally publishes the raw breakpoints t_k (unsorted) for fuse;
// interval membership there is the order-independent count #{k: t_k <= x}.
// ---------------------------------------------------------------------------
__global__ __launch_bounds__(256) void build_kernel(
        const float* __restrict__ W1,
        const float* __restrict__ b1,
        const float* __restrict__ W2,
        const float* __restrict__ b2,
        const float* __restrict__ spec,
        float* __restrict__ tvals,
        float2* __restrict__ tab) {
    const int row = blockIdx.x;
    const int tid = threadIdx.x;

    __shared__ float tsh[HID_DIM];
    __shared__ float ash[HID_DIM];
    __shared__ float csh[HID_DIM];

    float w = 0.0f, b = 0.0f, t = 0.0f;
    if (tid < HID_DIM) {
        w = W1[tid];
        b = b1[tid];
        t = (w != 0.0f) ? (-b / w) : __builtin_inff();
        tsh[tid] = t;
        if (row == 0) tvals[tid] = t;    // raw breakpoints for the fuse ballot
    }
    __syncthreads();
    if (tid < HID_DIM) {
        // stable rank of t among all breakpoints (defines interval membership)
        int r = 0;
        #pragma unroll 8
        for (int k2 = 0; k2 < HID_DIM; ++k2) {
            const float t2 = tsh[k2];
            if (t2 < t || (t2 == t && k2 < tid)) ++r;
        }

        float a, c;
        if (row <= HID_DIM) {
            const bool crossed = (r < row);              // t_k <= x in interval
            bool zpos;
            if (w > 0.0f)      zpos = crossed;
            else if (w < 0.0f) zpos = !crossed;
            else               zpos = (b >= 0.0f);
            const float s = zpos ? 1.0f : (SLOPE * SLOPE);
            a = s * w;
            c = s * b;
        } else {
            const int m = row - (HID_DIM + 1);
            const float e = spec[m * HID_DIM + tid];
            a = 0.0f;
            c = (e >= 0.0f) ? e : SLOPE * e;
        }
        ash[tid] = a;
        csh[tid] = c;
    }
    __syncthreads();

    // thread handles columns [4*tid .. 4*tid+3]
    float4 u = make_float4(0.f, 0.f, 0.f, 0.f);
    float4 v = make_float4(0.f, 0.f, 0.f, 0.f);
    #pragma unroll 4
    for (int k = 0; k < HID_DIM; ++k) {
        const float4 w2 = reinterpret_cast<const float4*>(W2 + (size_t)k * H_DIM)[tid];
        const float a = ash[k], c = csh[k];
        u.x = fmaf(a, w2.x, u.x);  v.x = fmaf(c, w2.x, v.x);
        u.y = fmaf(a, w2.y, u.y);  v.y = fmaf(c, w2.y, v.y);
        u.z = fmaf(a, w2.z, u.z);  v.z = fmaf(c, w2.z, v.z);
        u.w = fmaf(a, w2.w, u.w);  v.w = fmaf(c, w2.w, v.w);
    }
    const float4 bb = reinterpret_cast<const float4*>(b2)[tid];
    float4* trow = reinterpret_cast<float4*>(tab + (size_t)row * H_DIM);
    trow[2 * tid]     = make_float4(u.x, v.x + bb.x, u.y, v.y + bb.y);
    trow[2 * tid + 1] = make_float4(u.z, v.z + bb.z, u.w, v.w + bb.w);
}

// ---------------------------------------------------------------------------
// Kernel 2: fused gather + table MLP + pos add + LayerNorm.
// R9 frame (known 64.75us): NITER=8 tokens/wave, pos row in REGISTERS,
// gamma/beta in LDS, __launch_bounds__(256,2) (VGPR cap 256 - no spill).
// Single change vs R9: gene gather staged TWO iterations ahead (it is the
// L3/HBM long pole, ~500-900cy); tab stays 1-ahead (L2-hot); scalars 3-ahead.
// Register estimate ~170 < 256 cap.
// ---------------------------------------------------------------------------
__global__ __launch_bounds__(256, 2) void fuse_kernel(
        const int*   __restrict__ gene_ids,
        const float* __restrict__ expr,
        const float* __restrict__ gene_emb,
        const float* __restrict__ pos_emb,
        const float* __restrict__ gamma,
        const float* __restrict__ beta,
        const float* __restrict__ tvals,
        const float2* __restrict__ tab,
        float* __restrict__ out) {
    const int tid  = threadIdx.x;
    const int lane = tid & 63;
    const int w    = blockIdx.x * 4 + (tid >> 6);   // wave id = pos row, 0..4095

    __shared__ float4 gm_lds[H_DIM / 4];   // 4 KB
    __shared__ float4 bt_lds[H_DIM / 4];   // 4 KB
    gm_lds[tid] = reinterpret_cast<const float4*>(gamma)[tid];
    bt_lds[tid] = reinterpret_cast<const float4*>(beta)[tid];

    // breakpoints + pos row: once per wave (pos stays in registers, as R9)
    const float tka = tvals[lane];
    const float tkb = tvals[lane + 64];
    const float4* pp = reinterpret_cast<const float4*>(pos_emb + (size_t)w * H_DIM);
    float4 p[4];
    #pragma unroll
    for (int q = 0; q < 4; ++q) p[q] = pp[lane + 64 * q];

    __syncthreads();    // gamma/beta staged

    // ---- prologue: scalars i=0..2; gene staging i=0,1; tab staging i=0
    float x0 = expr[w];
    int   g0 = gene_ids[w];
    float x1 = expr[w + S_LEN];
    int   g1 = gene_ids[w + S_LEN];
    float x2 = expr[w + 2 * S_LEN];
    int   g2 = gene_ids[w + 2 * S_LEN];

    float4 g_c[4], g_n1[4], ta_c[4], tb_c[4];
    {
        const float4* gpc = reinterpret_cast<const float4*>(gene_emb + (size_t)g0 * H_DIM);
        const float4* gpn = reinterpret_cast<const float4*>(gene_emb + (size_t)g1 * H_DIM);
        #pragma unroll
        for (int q = 0; q < 4; ++q) {
            const int f = lane + 64 * q;
            g_c[q]  = gpc[f];
            g_n1[q] = gpn[f];
        }
    }
    float xm_c;
    {
        const int rc = __popcll(__ballot(tka <= x0)) + __popcll(__ballot(tkb <= x0));
        const bool sc = (x0 < 0.0f);
        const int  mc = min(max(-((int)x0) - 1, 0), NSPEC - 1);
        const int  row = sc ? (HID_DIM + 1 + mc) : rc;
        xm_c = sc ? 0.0f : x0;
        const float4* tp = reinterpret_cast<const float4*>(tab + (size_t)row * H_DIM);
        #pragma unroll
        for (int q = 0; q < 4; ++q) {
            const int f = lane + 64 * q;
            ta_c[q] = tp[2 * f];
            tb_c[q] = tp[2 * f + 1];
        }
    }

    // pipeline scalar state: x_a = x[i+1], x_b = x[i+2], gid_b = gid[i+2]
    float x_a = x1, x_b = x2;
    int   gid_b = g2;

    #pragma unroll
    for (int i = 0; i < NITER; ++i) {
        const int t = w + i * S_LEN;

        // ---- scalars for i+3 (compile-time guard)
        float x_in = 0.0f;
        int   gid_in = 0;
        if (i + 3 < NITER) {
            x_in   = expr[t + 3 * S_LEN];
            gid_in = gene_ids[t + 3 * S_LEN];
        }

        // ---- gene staging for i+2 (2-ahead; the long-latency gather)
        float4 g_n2[4];
        if (i + 2 < NITER) {
            const float4* gp = reinterpret_cast<const float4*>(gene_emb + (size_t)gid_b * H_DIM);
            #pragma unroll
            for (int q = 0; q < 4; ++q) g_n2[q] = gp[lane + 64 * q];
        }

        // ---- tab staging for i+1 (1-ahead; L2-hot)
        float xm_n = 0.0f;
        float4 ta_n[4], tb_n[4];
        if (i + 1 < NITER) {
            const int rc = __popcll(__ballot(tka <= x_a)) + __popcll(__ballot(tkb <= x_a));
            const bool sn = (x_a < 0.0f);
            const int  mn = min(max(-((int)x_a) - 1, 0), NSPEC - 1);
            const int  rown = sn ? (HID_DIM + 1 + mn) : rc;
            xm_n = sn ? 0.0f : x_a;
            const float4* tp = reinterpret_cast<const float4*>(tab + (size_t)rown * H_DIM);
            #pragma unroll
            for (int q = 0; q < 4; ++q) {
                const int f = lane + 64 * q;
                ta_n[q] = tp[2 * f];
                tb_n[q] = tp[2 * f + 1];
            }
        }

        // ---- consume current staging: e + moments (pos from registers)
        float4 e[4];
        float s1 = 0.0f, s2 = 0.0f;
        #pragma unroll
        for (int q = 0; q < 4; ++q) {
            float4 ev;
            ev.x = g_c[q].x + fmaf(xm_c, ta_c[q].x, ta_c[q].y) + p[q].x;
            ev.y = g_c[q].y + fmaf(xm_c, ta_c[q].z, ta_c[q].w) + p[q].y;
            ev.z = g_c[q].z + fmaf(xm_c, tb_c[q].x, tb_c[q].y) + p[q].z;
            ev.w = g_c[q].w + fmaf(xm_c, tb_c[q].z, tb_c[q].w) + p[q].w;
            e[q] = ev;
            s1 += ev.x + ev.y + ev.z + ev.w;
            s2 += ev.x * ev.x + ev.y * ev.y + ev.z * ev.z + ev.w * ev.w;
        }

        // ---- 64-lane butterfly reduction (no LDS, no barrier)
        #pragma unroll
        for (int off = 32; off >= 1; off >>= 1) {
            s1 += __shfl_xor(s1, off, 64);
            s2 += __shfl_xor(s2, off, 64);
        }

        const float inv  = 1.0f / (float)H_DIM;
        const float mu   = s1 * inv;
        const float rsig = rsqrtf(s2 * inv - mu * mu + LN_EPS);

        // ---- LN epilogue: gamma/beta from LDS, NT stores
        vfloat4* op = reinterpret_cast<vfloat4*>(out + (size_t)t * H_DIM);
        #pragma unroll
        for (int q = 0; q < 4; ++q) {
            const int f = lane + 64 * q;
            const float4 gm = gm_lds[f];
            const float4 bt = bt_lds[f];
            vfloat4 o;
            o.x = fmaf((e[q].x - mu) * rsig, gm.x, bt.x);
            o.y = fmaf((e[q].y - mu) * rsig, gm.y, bt.y);
            o.z = fmaf((e[q].z - mu) * rsig, gm.z, bt.z);
            o.w = fmaf((e[q].w - mu) * rsig, gm.w, bt.w);
            __builtin_nontemporal_store(o, op + f);
        }

        // ---- shift pipeline (fully unrolled => compiler renames, no movs)
        xm_c  = xm_n;
        x_a   = x_b;
        x_b   = x_in;
        gid_b = gid_in;
        #pragma unroll
        for (int q = 0; q < 4; ++q) {
            g_c[q]  = g_n1[q];
            g_n1[q] = g_n2[q];
            ta_c[q] = ta_n[q];
            tb_c[q] = tb_n[q];
        }
    }
}

// ---------------------------------------------------------------------------
extern "C" void kernel_launch(void* const* d_in, const int* in_sizes, int n_in,
                              void* d_out, int out_size, void* d_ws, size_t ws_size,
                              hipStream_t stream) {
    const int*   gene_ids = (const int*)  d_in[0];
    const float* expr     = (const float*)d_in[1];
    const float* gene_emb = (const float*)d_in[2];
    const float* W1       = (const float*)d_in[3];
    const float* b1       = (const float*)d_in[4];
    const float* W2       = (const float*)d_in[5];
    const float* b2       = (const float*)d_in[6];
    const float* spec     = (const float*)d_in[7];
    const float* pos_emb  = (const float*)d_in[8];
    const float* gamma    = (const float*)d_in[9];
    const float* beta     = (const float*)d_in[10];
    float* out = (float*)d_out;

    // workspace layout
    const size_t tab_bytes = (size_t)NROWS * H_DIM * sizeof(float2);  // ~1.07 MB
    float2* tab   = (float2*)d_ws;
    float*  tvals = (float*)((char*)d_ws + tab_bytes);

    const int n_tokens = in_sizes[0];       // B*S = 32768
    const int nwaves   = n_tokens / NITER;  // 4096 waves, one pos row each

    build_kernel<<<NROWS, 256, 0, stream>>>(W1, b1, W2, b2, spec, tvals, tab);
    fuse_kernel<<<nwaves / 4, 256, 0, stream>>>(gene_ids, expr, gene_emb, pos_emb,
                                                gamma, beta, tvals, tab, out);
}